// Round 4
// baseline (606.395 us; speedup 1.0000x reference)
//
#include <hip/hip_runtime.h>

#define NN 100000   // nodes
#define NE 1600000  // edges
#define NR 8        // relations
#define DD 128      // feature dim
#define NKEY (NN * NR)               // 800000 (dst,rel) keys
#define NBLK ((NKEY + 1023) / 1024)  // 782 scan blocks
#define RSTRIDE 588                  // sAgg row stride in dwords: 588%32=12 -> <=2-way
                                     // bank aliasing on ds_read_b128 (580%32=4 was 4-way);
                                     // 588%4==0 keeps 16B alignment for b128

typedef __attribute__((ext_vector_type(8))) short short8;
typedef __attribute__((ext_vector_type(4))) float f32x4;

__device__ __forceinline__ float bf2f(unsigned short u) {
  union { unsigned int i; float f; } c; c.i = ((unsigned int)u) << 16; return c.f;
}
__device__ __forceinline__ unsigned short f2bf(float f) {
  union { float f; unsigned int i; } c; c.f = f;
  unsigned int u = c.i;
  return (unsigned short)((u + 0x7FFFu + ((u >> 16) & 1u)) >> 16);  // RNE
}

// ---- fused preprocessing: x-cast + counter-zero + weight transpose ----------
// Three independent original kernels (k_cast/k_zero/k_wtrans) under one grid:
// saves 2 launch gaps. Block ranges: [0,12500) cast, [12500,15625) zero,
// [15625,16777) wtrans. (Independently verified: CAST_B=12500 exact,
// ZERO_B=3125 exact since NKEY=256*3125, WT blocks=1152 exact.)
__global__ __launch_bounds__(256) void k_prep(
    const float* __restrict__ x, unsigned short* __restrict__ xb,
    const float* __restrict__ W1, const float* __restrict__ root1,
    const float* __restrict__ W2, const float* __restrict__ root2,
    unsigned short* __restrict__ wbf, int* __restrict__ cnt) {
  const int CAST_B = (NN * DD / 4 + 255) / 256;   // 12500
  const int ZERO_B = (NKEY + 255) / 256;          // 3125
  int b = blockIdx.x, t = threadIdx.x;
  if (b < CAST_B) {
    int i = b * 256 + t;
    if (i < NN * DD / 4) {
      float4 f = ((const float4*)x)[i];
      ushort4 u;
      u.x = f2bf(f.x); u.y = f2bf(f.y); u.z = f2bf(f.z); u.w = f2bf(f.w);
      ((ushort4*)xb)[i] = u;
    }
  } else if (b < CAST_B + ZERO_B) {
    int i = (b - CAST_B) * 256 + t;
    if (i < NKEY) cnt[i] = 0;
  } else {
    int idx = (b - CAST_B - ZERO_B) * 256 + t;    // 2*9*16384 total, exact
    int layer = idx / (9 * 16384);
    int rem = idx % (9 * 16384);
    int r = rem / 16384;
    int nk = rem % 16384;
    int n = nk >> 7, k = nk & 127;
    float v;
    if (r < 8) v = (layer ? W2 : W1)[r * 16384 + k * 128 + n];
    else       v = (layer ? root2 : root1)[k * 128 + n];
    wbf[idx] = f2bf(v);
  }
}

__global__ __launch_bounds__(256) void k_count(
    const int* __restrict__ ei, const int* __restrict__ et, int* __restrict__ cnt) {
  int e = blockIdx.x * 256 + threadIdx.x;
  if (e < NE) {
    int dst = ei[NE + e];
    int r = et[e];
    atomicAdd(&cnt[dst * NR + r], 1);
  }
}

// hierarchical exclusive scan over NKEY elements — shfl-based
__global__ __launch_bounds__(1024) void k_scan1(
    const int* __restrict__ cnt, int* __restrict__ offs, int* __restrict__ bsum) {
  __shared__ int sw[16];
  int t = threadIdx.x, b = blockIdx.x;
  int lane = t & 63, wid = t >> 6;
  int i = b * 1024 + t;
  int v = (i < NKEY) ? cnt[i] : 0;
  int x = v;
#pragma unroll
  for (int o = 1; o < 64; o <<= 1) {
    int y = __shfl_up(x, o);
    if (lane >= o) x += y;
  }
  if (lane == 63) sw[wid] = x;
  __syncthreads();
  if (wid == 0) {
    int s = (lane < 16) ? sw[lane] : 0;
#pragma unroll
    for (int o = 1; o < 16; o <<= 1) {
      int y = __shfl_up(s, o);
      if (lane >= o) s += y;
    }
    if (lane < 16) sw[lane] = s;
  }
  __syncthreads();
  int base = (wid > 0) ? sw[wid - 1] : 0;
  if (i < NKEY) offs[i] = base + x - v;
  if (t == 1023) bsum[b] = base + x;
}

__global__ __launch_bounds__(1024) void k_scan2(int* __restrict__ bsum) {
  __shared__ int sw[16];
  int t = threadIdx.x;
  int lane = t & 63, wid = t >> 6;
  int v = (t < NBLK) ? bsum[t] : 0;
  int x = v;
#pragma unroll
  for (int o = 1; o < 64; o <<= 1) {
    int y = __shfl_up(x, o);
    if (lane >= o) x += y;
  }
  if (lane == 63) sw[wid] = x;
  __syncthreads();
  if (wid == 0) {
    int s = (lane < 16) ? sw[lane] : 0;
#pragma unroll
    for (int o = 1; o < 16; o <<= 1) {
      int y = __shfl_up(s, o);
      if (lane >= o) s += y;
    }
    if (lane < 16) sw[lane] = s;
  }
  __syncthreads();
  int base = (wid > 0) ? sw[wid - 1] : 0;
  if (t < NBLK) bsum[t] = base + x - v;
}

__global__ __launch_bounds__(256) void k_scan3(
    int* __restrict__ offs, const int* __restrict__ bsum, int* __restrict__ csr) {
  int i = blockIdx.x * 256 + threadIdx.x;
  if (i < NKEY) offs[i] += bsum[i >> 10];
  if (i == 0) offs[NKEY] = NE;
  if (i < 256) csr[NE + i] = 0;                    // zero pad for deeper window prefetch
}

__global__ __launch_bounds__(256) void k_csr(
    const int* __restrict__ ei, const int* __restrict__ et,
    const int* __restrict__ offs, int* __restrict__ cnt, int* __restrict__ csr) {
  int e = blockIdx.x * 256 + threadIdx.x;
  if (e < NE) {
    int src = ei[e];
    int key = ei[NE + e] * NR + et[e];
    int old = atomicSub(&cnt[key], 1);
    csr[offs[key] + old - 1] = src;
  }
}

// ---- fused per-layer kernel -------------------------------------------------
// Block (512 thr, 8 waves) owns 32 dst nodes (75.3 KB LDS, 2 blocks/CU).
// Wave w owns 4 nodes = keys 32w..32w+31 (contiguous csr range).
// R4 changes vs R3 (174.8 us):
//  * DEPTH 16 ping-pong (was 8): outstanding gathers oscillate 16<->32 (was
//    8<->16). R1+R3 evidence says the gather is capped by per-CU outstanding
//    misses, not wave count -- keep the miss queue full through consumes.
//  * RSTRIDE 580->588: A-fragment ds_read_b128 bank aliasing 4-way -> <=2-way
//    (2-way is free); SQ_LDS_BANK_CONFLICT was 7.2M cy (~6.7%/CU).
template <int RELU, int OUTBF>
__global__ __launch_bounds__(512, 4) void k_fused(
    const unsigned short* __restrict__ xb,   // [N][128] bf16
    const unsigned short* __restrict__ wl,   // [9][128][128] n-major bf16
    const int* __restrict__ offs, const int* __restrict__ csr,
    const float* __restrict__ bias, void* __restrict__ outp) {
  __shared__ unsigned int sAgg32[32 * RSTRIDE];    // [32 nodes][9*128+..] bf16, 75264 B
  const unsigned short* sAggH = (const unsigned short*)sAgg32;

  const int tid = threadIdx.x;
  const int w = tid >> 6;                          // 8 waves
  const int lane = tid & 63;
  const int m = lane & 15, q = lane >> 4;
  const int n0 = blockIdx.x * 32;
  const int k0 = n0 * NR;

  // this wave's 33 key offsets, one per lane (lane 0..32)
  int oidx = k0 + 32 * w + lane;
  if (oidx > NKEY) oidx = NKEY;
  const int offv = offs[oidx];
  const int p0 = __builtin_amdgcn_readlane(offv, 0);
  const int p1 = __builtin_amdgcn_readlane(offv, 32);

  // root row for this wave's 4 nodes: xb -> sAgg slot 8 (bf16 passthrough)
#pragma unroll
  for (int i = 0; i < 4; i++) {
    int node = 4 * w + i;
    unsigned int v = *(const unsigned int*)(xb + (size_t)(n0 + node) * DD + 2 * lane);
    sAgg32[node * RSTRIDE + 8 * 64 + lane] = v;
  }

  // ---- edge phase ----
  int kloc = 0;
  int kbeg = p0;
  int kend = __builtin_amdgcn_readlane(offv, 1);
  float ax = 0.f, ay = 0.f;

  // csr window: pv0 covers [wbase, wbase+64) and is the only one read;
  // pv1 covers [wbase+64, wbase+128), a pure prefetch swapped in at the
  // 64-edge boundary (its load is then 64 edges old -> long complete).
  int wbase = p0;
  int pv0 = csr[wbase + lane];
  int pv1 = csr[wbase + 64 + lane];

#define ISSUE16(DST, NB) do {                                                \
    if ((NB) - wbase == 64) {                                                \
      wbase += 64; pv0 = pv1; pv1 = csr[wbase + 64 + lane];                  \
    }                                                                        \
    const int ib_ = (NB) - wbase;                                            \
    _Pragma("unroll") for (int j_ = 0; j_ < 16; j_++) {                      \
      unsigned s_ = (unsigned)__builtin_amdgcn_readlane(pv0, ib_ + j_);      \
      (DST)[j_] = *(const ushort2*)(xb + (size_t)s_ * DD + 2 * lane);        \
    }                                                                        \
  } while (0)

#define CONSUME16(V, B0) do {                                                \
    _Pragma("unroll") for (int j_ = 0; j_ < 16; j_++) {                      \
      if ((B0) + j_ < p1) {                                                  \
        while ((B0) + j_ >= kend) {                                          \
          float nm_ = __builtin_amdgcn_rcpf(fmaxf((float)(kend - kbeg), 1.f)); \
          unsigned lo_ = f2bf(ax * nm_), hi_ = f2bf(ay * nm_);               \
          int node_ = 4 * w + (kloc >> 3);                                   \
          sAgg32[node_ * RSTRIDE + (kloc & 7) * 64 + lane] = lo_ | (hi_ << 16); \
          ax = 0.f; ay = 0.f;                                                \
          kloc++;                                                            \
          kbeg = kend;                                                       \
          kend = __builtin_amdgcn_readlane(offv, kloc + 1);                  \
        }                                                                    \
        ax += bf2f((V)[j_].x);                                               \
        ay += bf2f((V)[j_].y);                                               \
      }                                                                      \
    }                                                                        \
  } while (0)

  ushort2 va[16], vb[16];
  ISSUE16(va, p0);                                 // prologue: edges p0..p0+15

  for (int base = p0; base < p1; base += 32) {
    ISSUE16(vb, base + 16);                        // issue edges base+16..+31
    CONSUME16(va, base);                           // consume edges base..+15
    ISSUE16(va, base + 32);                        // issue edges base+32..+47
    CONSUME16(vb, base + 16);                      // consume edges base+16..+31
  }
  // drain remaining keys (incl. empty)
  while (kloc < 32) {
    float nm = __builtin_amdgcn_rcpf(fmaxf((float)(kend - kbeg), 1.f));
    unsigned lo = f2bf(ax * nm), hi = f2bf(ay * nm);
    int node = 4 * w + (kloc >> 3);
    sAgg32[node * RSTRIDE + (kloc & 7) * 64 + lane] = lo | (hi << 16);
    ax = 0.f; ay = 0.f;
    kloc++;
    kbeg = kend;
    kend = (kloc < 32) ? __builtin_amdgcn_readlane(offv, kloc + 1) : kend;
  }
#undef ISSUE16
#undef CONSUME16
  __syncthreads();

  // ---- MFMA phase: wave w -> output cols 16w..16w+15, rows 0..31, 9 mats ----
  f32x4 acc0 = {0.f, 0.f, 0.f, 0.f};              // rows n0+0..15
  f32x4 acc1 = {0.f, 0.f, 0.f, 0.f};              // rows n0+16..31
  for (int mat = 0; mat < 9; mat++) {
    short8 a0[4], a1[4];
#pragma unroll
    for (int ks = 0; ks < 4; ks++) {
      a0[ks] = *(const short8*)(sAggH + m * (2 * RSTRIDE) + mat * 128 + ks * 32 + q * 8);
      a1[ks] = *(const short8*)(sAggH + (m + 16) * (2 * RSTRIDE) + mat * 128 + ks * 32 + q * 8);
    }
    const unsigned short* wr = wl + mat * DD * DD;
#pragma unroll
    for (int ks = 0; ks < 4; ks++) {
      short8 b = *(const short8*)(wr + (w * 16 + m) * DD + ks * 32 + q * 8);
      acc0 = __builtin_amdgcn_mfma_f32_16x16x32_bf16(a0[ks], b, acc0, 0, 0, 0);
      acc1 = __builtin_amdgcn_mfma_f32_16x16x32_bf16(a1[ks], b, acc1, 0, 0, 0);
    }
  }

  // epilogue: C/D row = q*4+i (+16 for acc1), col = w*16+m
  {
    const int c0 = w * 16 + m;
    const float bv = bias[c0];
#pragma unroll
    for (int i = 0; i < 4; i++) {
      int row0 = n0 + q * 4 + i;
      int row1 = row0 + 16;
      float v0 = acc0[i] + bv, v1 = acc1[i] + bv;
      if (RELU) { v0 = fmaxf(v0, 0.f); v1 = fmaxf(v1, 0.f); }
      if (OUTBF) {
        ((unsigned short*)outp)[(size_t)row0 * DD + c0] = f2bf(v0);
        ((unsigned short*)outp)[(size_t)row1 * DD + c0] = f2bf(v1);
      } else {
        ((float*)outp)[(size_t)row0 * DD + c0] = v0;
        ((float*)outp)[(size_t)row1 * DD + c0] = v1;
      }
    }
  }
}

// ---- launch -----------------------------------------------------------------

extern "C" void kernel_launch(void* const* d_in, const int* in_sizes, int n_in,
                              void* d_out, int out_size, void* d_ws, size_t ws_size,
                              hipStream_t stream) {
  const float* x     = (const float*)d_in[0];
  const int*   ei    = (const int*)d_in[1];
  const int*   et    = (const int*)d_in[2];
  const float* W1    = (const float*)d_in[3];
  const float* root1 = (const float*)d_in[4];
  const float* b1    = (const float*)d_in[5];
  const float* W2    = (const float*)d_in[6];
  const float* root2 = (const float*)d_in[7];
  const float* b2    = (const float*)d_in[8];
  float* out = (float*)d_out;

  char* p = (char*)d_ws;
  unsigned short* xb1 = (unsigned short*)p; p += (size_t)NN * DD * 2;   // 25.6 MB
  unsigned short* xb2 = (unsigned short*)p; p += (size_t)NN * DD * 2;   // 25.6 MB
  unsigned short* wbf = (unsigned short*)p; p += (size_t)2 * 9 * DD * DD * 2;
  int* cnt  = (int*)p; p += (size_t)NKEY * 4;                           // 3.2 MB
  int* offs = (int*)p; p += (size_t)(NKEY + 16) * 4;                    // 3.2 MB
  int* bsum = (int*)p; p += (size_t)800 * 4;                            // NBLK=782
  int* csr  = (int*)p; p += (size_t)(NE + 256) * 4;                     // 6.4 MB (+zeroed pad)
  // total ~= 64 MB

  const int PREP_B = (NN * DD / 4 + 255) / 256 + (NKEY + 255) / 256 + (2 * 9 * 16384) / 256;
  k_prep<<<PREP_B, 256, 0, stream>>>(x, xb1, W1, root1, W2, root2, wbf, cnt);
  k_count<<<(NE + 255) / 256, 256, 0, stream>>>(ei, et, cnt);
  k_scan1<<<NBLK, 1024, 0, stream>>>(cnt, offs, bsum);
  k_scan2<<<1, 1024, 0, stream>>>(bsum);
  k_scan3<<<(NKEY + 255) / 256, 256, 0, stream>>>(offs, bsum, csr);
  k_csr<<<(NE + 255) / 256, 256, 0, stream>>>(ei, et, offs, cnt, csr);

  dim3 fgrid(NN / 32);   // 3125
  k_fused<1, 1><<<fgrid, 512, 0, stream>>>(xb1, wbf, offs, csr, b1, (void*)xb2);
  k_fused<0, 0><<<fgrid, 512, 0, stream>>>(xb2, wbf + 9 * DD * DD, offs, csr, b2, (void*)out);
}

// Round 5
// 556.833 us; speedup vs baseline: 1.0890x; 1.0890x over previous
//
#include <hip/hip_runtime.h>

#define NN 100000   // nodes
#define NE 1600000  // edges
#define NR 8        // relations
#define DD 128      // feature dim
#define NKEY (NN * NR)               // 800000 (dst,rel) keys
#define NBLK ((NKEY + 1023) / 1024)  // 782 scan blocks
#define RSTRIDE 580                  // sAgg row stride in dwords (R3-proven)

typedef __attribute__((ext_vector_type(8))) short short8;
typedef __attribute__((ext_vector_type(4))) float f32x4;

__device__ __forceinline__ float bf2f(unsigned short u) {
  union { unsigned int i; float f; } c; c.i = ((unsigned int)u) << 16; return c.f;
}
__device__ __forceinline__ unsigned short f2bf(float f) {
  union { float f; unsigned int i; } c; c.f = f;
  unsigned int u = c.i;
  return (unsigned short)((u + 0x7FFFu + ((u >> 16) & 1u)) >> 16);  // RNE
}

// ---- fused preprocessing: x-cast + counter-zero + weight transpose ----------
__global__ __launch_bounds__(256) void k_prep(
    const float* __restrict__ x, unsigned short* __restrict__ xb,
    const float* __restrict__ W1, const float* __restrict__ root1,
    const float* __restrict__ W2, const float* __restrict__ root2,
    unsigned short* __restrict__ wbf, int* __restrict__ cnt) {
  const int CAST_B = (NN * DD / 4 + 255) / 256;   // 12500
  const int ZERO_B = (NKEY + 255) / 256;          // 3125
  int b = blockIdx.x, t = threadIdx.x;
  if (b < CAST_B) {
    int i = b * 256 + t;
    if (i < NN * DD / 4) {
      float4 f = ((const float4*)x)[i];
      ushort4 u;
      u.x = f2bf(f.x); u.y = f2bf(f.y); u.z = f2bf(f.z); u.w = f2bf(f.w);
      ((ushort4*)xb)[i] = u;
    }
  } else if (b < CAST_B + ZERO_B) {
    int i = (b - CAST_B) * 256 + t;
    if (i < NKEY) cnt[i] = 0;
  } else {
    int idx = (b - CAST_B - ZERO_B) * 256 + t;    // 2*9*16384 total, exact
    int layer = idx / (9 * 16384);
    int rem = idx % (9 * 16384);
    int r = rem / 16384;
    int nk = rem % 16384;
    int n = nk >> 7, k = nk & 127;
    float v;
    if (r < 8) v = (layer ? W2 : W1)[r * 16384 + k * 128 + n];
    else       v = (layer ? root2 : root1)[k * 128 + n];
    wbf[idx] = f2bf(v);
  }
}

// count + per-edge rank: the returning atomicAdd gives each edge a unique
// within-key slot, written sequentially. This moves the "atomic with return"
// round-trip out of k_csr (which was paying the same ~32-line/CU concurrency
// wall as the gathers) and makes k_csr a pure fire-and-forget scatter.
__global__ __launch_bounds__(256) void k_count(
    const int* __restrict__ ei, const int* __restrict__ et,
    int* __restrict__ cnt, int* __restrict__ rank) {
  int e = blockIdx.x * 256 + threadIdx.x;
  if (e < NE) {
    int dst = ei[NE + e];
    int r = et[e];
    rank[e] = atomicAdd(&cnt[dst * NR + r], 1);
  }
}

// hierarchical exclusive scan over NKEY elements — shfl-based
__global__ __launch_bounds__(1024) void k_scan1(
    const int* __restrict__ cnt, int* __restrict__ offs, int* __restrict__ bsum) {
  __shared__ int sw[16];
  int t = threadIdx.x, b = blockIdx.x;
  int lane = t & 63, wid = t >> 6;
  int i = b * 1024 + t;
  int v = (i < NKEY) ? cnt[i] : 0;
  int x = v;
#pragma unroll
  for (int o = 1; o < 64; o <<= 1) {
    int y = __shfl_up(x, o);
    if (lane >= o) x += y;
  }
  if (lane == 63) sw[wid] = x;
  __syncthreads();
  if (wid == 0) {
    int s = (lane < 16) ? sw[lane] : 0;
#pragma unroll
    for (int o = 1; o < 16; o <<= 1) {
      int y = __shfl_up(s, o);
      if (lane >= o) s += y;
    }
    if (lane < 16) sw[lane] = s;
  }
  __syncthreads();
  int base = (wid > 0) ? sw[wid - 1] : 0;
  if (i < NKEY) offs[i] = base + x - v;
  if (t == 1023) bsum[b] = base + x;
}

__global__ __launch_bounds__(1024) void k_scan2(int* __restrict__ bsum) {
  __shared__ int sw[16];
  int t = threadIdx.x;
  int lane = t & 63, wid = t >> 6;
  int v = (t < NBLK) ? bsum[t] : 0;
  int x = v;
#pragma unroll
  for (int o = 1; o < 64; o <<= 1) {
    int y = __shfl_up(x, o);
    if (lane >= o) x += y;
  }
  if (lane == 63) sw[wid] = x;
  __syncthreads();
  if (wid == 0) {
    int s = (lane < 16) ? sw[lane] : 0;
#pragma unroll
    for (int o = 1; o < 16; o <<= 1) {
      int y = __shfl_up(s, o);
      if (lane >= o) s += y;
    }
    if (lane < 16) sw[lane] = s;
  }
  __syncthreads();
  int base = (wid > 0) ? sw[wid - 1] : 0;
  if (t < NBLK) bsum[t] = base + x - v;
}

__global__ __launch_bounds__(256) void k_scan3(
    int* __restrict__ offs, const int* __restrict__ bsum, int* __restrict__ csr) {
  int i = blockIdx.x * 256 + threadIdx.x;
  if (i < NKEY) offs[i] += bsum[i >> 10];
  if (i == 0) offs[NKEY] = NE;
  if (i < 192) csr[NE + i] = 0;                    // zero pad for window prefetch
}

// pure scatter, no atomics: slot = offs[key] + rank[e] (unique by construction)
__global__ __launch_bounds__(256) void k_csr(
    const int* __restrict__ ei, const int* __restrict__ et,
    const int* __restrict__ offs, const int* __restrict__ rank,
    int* __restrict__ csr) {
  int e = blockIdx.x * 256 + threadIdx.x;
  if (e < NE) {
    int src = ei[e];
    int key = ei[NE + e] * NR + et[e];
    csr[offs[key] + rank[e]] = src;
  }
}

// ---- fused per-layer kernel (R3-proven: DEPTH8 ping-pong, 32 nodes/block) ---
template <int RELU, int OUTBF>
__global__ __launch_bounds__(512, 4) void k_fused(
    const unsigned short* __restrict__ xb,   // [N][128] bf16
    const unsigned short* __restrict__ wl,   // [9][128][128] n-major bf16
    const int* __restrict__ offs, const int* __restrict__ csr,
    const float* __restrict__ bias, void* __restrict__ outp) {
  __shared__ unsigned int sAgg32[32 * RSTRIDE];    // [32 nodes][9*128+8] bf16, 74240 B
  const unsigned short* sAggH = (const unsigned short*)sAgg32;

  const int tid = threadIdx.x;
  const int w = tid >> 6;                          // 8 waves
  const int lane = tid & 63;
  const int m = lane & 15, q = lane >> 4;
  const int n0 = blockIdx.x * 32;
  const int k0 = n0 * NR;

  // this wave's 33 key offsets, one per lane (lane 0..32)
  int oidx = k0 + 32 * w + lane;
  if (oidx > NKEY) oidx = NKEY;
  const int offv = offs[oidx];
  const int p0 = __builtin_amdgcn_readlane(offv, 0);
  const int p1 = __builtin_amdgcn_readlane(offv, 32);

  // root row for this wave's 4 nodes: xb -> sAgg slot 8 (bf16 passthrough)
#pragma unroll
  for (int i = 0; i < 4; i++) {
    int node = 4 * w + i;
    unsigned int v = *(const unsigned int*)(xb + (size_t)(n0 + node) * DD + 2 * lane);
    sAgg32[node * RSTRIDE + 8 * 64 + lane] = v;
  }

  // ---- edge phase ----
  int kloc = 0;
  int kbeg = p0;
  int kend = __builtin_amdgcn_readlane(offv, 1);
  float ax = 0.f, ay = 0.f;

  // csr window: pv0 covers [wbase, wbase+64) (the only one read); pv1 covers
  // [wbase+64, wbase+128), a pure prefetch swapped in at the 64-edge boundary.
  int wbase = p0;
  int pv0 = csr[wbase + lane];
  int pv1 = csr[wbase + 64 + lane];

#define ISSUE8(DST, NB) do {                                                 \
    if ((NB) - wbase == 64) {                                                \
      wbase += 64; pv0 = pv1; pv1 = csr[wbase + 64 + lane];                  \
    }                                                                        \
    const int ib_ = (NB) - wbase;                                            \
    _Pragma("unroll") for (int j_ = 0; j_ < 8; j_++) {                       \
      unsigned s_ = (unsigned)__builtin_amdgcn_readlane(pv0, ib_ + j_);      \
      (DST)[j_] = *(const ushort2*)(xb + (size_t)s_ * DD + 2 * lane);        \
    }                                                                        \
  } while (0)

#define CONSUME8(V, B0) do {                                                 \
    _Pragma("unroll") for (int j_ = 0; j_ < 8; j_++) {                       \
      if ((B0) + j_ < p1) {                                                  \
        while ((B0) + j_ >= kend) {                                          \
          float nm_ = __builtin_amdgcn_rcpf(fmaxf((float)(kend - kbeg), 1.f)); \
          unsigned lo_ = f2bf(ax * nm_), hi_ = f2bf(ay * nm_);               \
          int node_ = 4 * w + (kloc >> 3);                                   \
          sAgg32[node_ * RSTRIDE + (kloc & 7) * 64 + lane] = lo_ | (hi_ << 16); \
          ax = 0.f; ay = 0.f;                                                \
          kloc++;                                                            \
          kbeg = kend;                                                       \
          kend = __builtin_amdgcn_readlane(offv, kloc + 1);                  \
        }                                                                    \
        ax += bf2f((V)[j_].x);                                               \
        ay += bf2f((V)[j_].y);                                               \
      }                                                                      \
    }                                                                        \
  } while (0)

  ushort2 va[8], vb[8];
  ISSUE8(va, p0);                                  // prologue: edges p0..p0+7

  for (int base = p0; base < p1; base += 16) {
    ISSUE8(vb, base + 8);                          // issue edges base+8..+15
    CONSUME8(va, base);                            // consume edges base..+7
    ISSUE8(va, base + 16);                         // issue edges base+16..+23
    CONSUME8(vb, base + 8);                        // consume edges base+8..+15
  }
  // drain remaining keys (incl. empty)
  while (kloc < 32) {
    float nm = __builtin_amdgcn_rcpf(fmaxf((float)(kend - kbeg), 1.f));
    unsigned lo = f2bf(ax * nm), hi = f2bf(ay * nm);
    int node = 4 * w + (kloc >> 3);
    sAgg32[node * RSTRIDE + (kloc & 7) * 64 + lane] = lo | (hi << 16);
    ax = 0.f; ay = 0.f;
    kloc++;
    kbeg = kend;
    kend = (kloc < 32) ? __builtin_amdgcn_readlane(offv, kloc + 1) : kend;
  }
#undef ISSUE8
#undef CONSUME8
  __syncthreads();

  // ---- MFMA phase: wave w -> output cols 16w..16w+15, rows 0..31, 9 mats ----
  f32x4 acc0 = {0.f, 0.f, 0.f, 0.f};              // rows n0+0..15
  f32x4 acc1 = {0.f, 0.f, 0.f, 0.f};              // rows n0+16..31
  for (int mat = 0; mat < 9; mat++) {
    short8 a0[4], a1[4];
#pragma unroll
    for (int ks = 0; ks < 4; ks++) {
      a0[ks] = *(const short8*)(sAggH + m * (2 * RSTRIDE) + mat * 128 + ks * 32 + q * 8);
      a1[ks] = *(const short8*)(sAggH + (m + 16) * (2 * RSTRIDE) + mat * 128 + ks * 32 + q * 8);
    }
    const unsigned short* wr = wl + mat * DD * DD;
#pragma unroll
    for (int ks = 0; ks < 4; ks++) {
      short8 b = *(const short8*)(wr + (w * 16 + m) * DD + ks * 32 + q * 8);
      acc0 = __builtin_amdgcn_mfma_f32_16x16x32_bf16(a0[ks], b, acc0, 0, 0, 0);
      acc1 = __builtin_amdgcn_mfma_f32_16x16x32_bf16(a1[ks], b, acc1, 0, 0, 0);
    }
  }

  // epilogue: C/D row = q*4+i (+16 for acc1), col = w*16+m
  {
    const int c0 = w * 16 + m;
    const float bv = bias[c0];
#pragma unroll
    for (int i = 0; i < 4; i++) {
      int row0 = n0 + q * 4 + i;
      int row1 = row0 + 16;
      float v0 = acc0[i] + bv, v1 = acc1[i] + bv;
      if (RELU) { v0 = fmaxf(v0, 0.f); v1 = fmaxf(v1, 0.f); }
      if (OUTBF) {
        ((unsigned short*)outp)[(size_t)row0 * DD + c0] = f2bf(v0);
        ((unsigned short*)outp)[(size_t)row1 * DD + c0] = f2bf(v1);
      } else {
        ((float*)outp)[(size_t)row0 * DD + c0] = v0;
        ((float*)outp)[(size_t)row1 * DD + c0] = v1;
      }
    }
  }
}

// ---- launch -----------------------------------------------------------------

extern "C" void kernel_launch(void* const* d_in, const int* in_sizes, int n_in,
                              void* d_out, int out_size, void* d_ws, size_t ws_size,
                              hipStream_t stream) {
  const float* x     = (const float*)d_in[0];
  const int*   ei    = (const int*)d_in[1];
  const int*   et    = (const int*)d_in[2];
  const float* W1    = (const float*)d_in[3];
  const float* root1 = (const float*)d_in[4];
  const float* b1    = (const float*)d_in[5];
  const float* W2    = (const float*)d_in[6];
  const float* root2 = (const float*)d_in[7];
  const float* b2    = (const float*)d_in[8];
  float* out = (float*)d_out;

  char* p = (char*)d_ws;
  unsigned short* xb1 = (unsigned short*)p; p += (size_t)NN * DD * 2;   // 25.6 MB
  unsigned short* xb2 = (unsigned short*)p; p += (size_t)NN * DD * 2;   // 25.6 MB
  unsigned short* wbf = (unsigned short*)p; p += (size_t)2 * 9 * DD * DD * 2;
  int* cnt  = (int*)p; p += (size_t)NKEY * 4;                           // 3.2 MB
  int* offs = (int*)p; p += (size_t)(NKEY + 16) * 4;                    // 3.2 MB
  int* bsum = (int*)p; p += (size_t)800 * 4;                            // NBLK=782
  int* rank = (int*)p; p += (size_t)NE * 4;                             // 6.4 MB
  int* csr  = (int*)p; p += (size_t)(NE + 192) * 4;                     // 6.4 MB (+zeroed pad)
  // total ~= 71 MB

  const int PREP_B = (NN * DD / 4 + 255) / 256 + (NKEY + 255) / 256 + (2 * 9 * 16384) / 256;
  k_prep<<<PREP_B, 256, 0, stream>>>(x, xb1, W1, root1, W2, root2, wbf, cnt);
  k_count<<<(NE + 255) / 256, 256, 0, stream>>>(ei, et, cnt, rank);
  k_scan1<<<NBLK, 1024, 0, stream>>>(cnt, offs, bsum);
  k_scan2<<<1, 1024, 0, stream>>>(bsum);
  k_scan3<<<(NKEY + 255) / 256, 256, 0, stream>>>(offs, bsum, csr);
  k_csr<<<(NE + 255) / 256, 256, 0, stream>>>(ei, et, offs, rank, csr);

  dim3 fgrid(NN / 32);   // 3125
  k_fused<1, 1><<<fgrid, 512, 0, stream>>>(xb1, wbf, offs, csr, b1, (void*)xb2);
  k_fused<0, 0><<<fgrid, 512, 0, stream>>>(xb2, wbf + 9 * DD * DD, offs, csr, b2, (void*)out);
}